// Round 14
// baseline (331.738 us; speedup 1.0000x reference)
//
#include <hip/hip_runtime.h>
#include <hip/hip_bf16.h>

typedef __attribute__((ext_vector_type(4))) float f32x4;
typedef __attribute__((ext_vector_type(8))) short short8;
typedef __attribute__((ext_vector_type(4))) unsigned short us4;
typedef unsigned short u16;

#define DEVI __device__ __forceinline__

#define BB 128      // batches
#define NN 256      // input patches per batch
#define MMEM 8      // memory tokens
#define DD 768      // embed dim
#define TT 264      // N + M
#define TP 320      // P/Vt col padding (zeros in cols 264..319)
#define SP 384      // S col padding (3 x 128 tiles)
#define AROWS2 33024  // 258*128 rows for G1 (x .. memory .. zero pad)

DEVI u16 f2bf(float f) {
  __hip_bfloat16 b = __float2bfloat16(f);
  u16 u; __builtin_memcpy(&u, &b, 2); return u;
}

DEVI float bf2f(u16 u) {
  unsigned int v = ((unsigned int)u) << 16;
  float f; __builtin_memcpy(&f, &v, 4); return f;
}

DEVI void gload_lds16(const void* g, void* l) {
  __builtin_amdgcn_global_load_lds((const __attribute__((address_space(1))) void*)g,
                                   (__attribute__((address_space(3))) void*)l, 16, 0, 0);
}

// ---------------- conversion kernels ----------------

__global__ __launch_bounds__(256)
void conv_x(const float* __restrict__ x, const float* __restrict__ mem, u16* __restrict__ Ab) {
  const long total4 = (long)AROWS2 * DD / 4;
  for (long i = (long)blockIdx.x * blockDim.x + threadIdx.x; i < total4;
       i += (long)gridDim.x * blockDim.x) {
    long e = i * 4;
    int row = (int)(e / DD);
    int cb  = (int)(e % DD);
    f32x4 v = {0.f, 0.f, 0.f, 0.f};
    if (row < BB * NN)             v = *(const f32x4*)(x   + (size_t)row * DD + cb);
    else if (row < BB * NN + MMEM) v = *(const f32x4*)(mem + (size_t)(row - BB * NN) * DD + cb);
    us4 o = {f2bf(v[0]), f2bf(v[1]), f2bf(v[2]), f2bf(v[3])};
    *(us4*)(Ab + e) = o;
  }
}

__global__ __launch_bounds__(256)
void conv_w(const float* __restrict__ Wq, const float* __restrict__ Wk,
            const float* __restrict__ Wv, const float* __restrict__ Wo,
            u16* __restrict__ Wqt, u16* __restrict__ Wkt,
            u16* __restrict__ Wvt, u16* __restrict__ Wot) {
  const int total = 4 * DD * DD;
  for (int i = blockIdx.x * blockDim.x + threadIdx.x; i < total;
       i += gridDim.x * blockDim.x) {
    int mat = i / (DD * DD), rem = i % (DD * DD);
    int j = rem / DD, d = rem % DD;
    const float* W = (mat == 0) ? Wq : (mat == 1) ? Wk : (mat == 2) ? Wv : Wo;
    u16* Wt = (mat == 0) ? Wqt : (mat == 1) ? Wkt : (mat == 2) ? Wvt : Wot;
    Wt[(size_t)j * DD + d] = f2bf(W[(size_t)d * DD + j]);
  }
}

// ================= 256x256 8-wave pipelined B^T GEMM (round-9 loop, proven) =================
// Used only for MODE 2 now: O = P @ Vt^T per batch.

#define BAR()    __builtin_amdgcn_s_barrier()
#define CFENCE() asm volatile("" ::: "memory")
#define VM2()    asm volatile("s_waitcnt vmcnt(2)" ::: "memory")
#define VMW0()   asm volatile("s_waitcnt vmcnt(0)" ::: "memory")

#define STG(gb, ld, isB, ss, rg, kt) do {                                       \
    const u16* _s = (gb) + (size_t)((rg) * 16 + srow) * (ld) + (kt) * 64 + scol;\
    char* _d = smem + (ss) * 65536 + (isB) * 32768 + (rg) * 2048;               \
    gload_lds16(_s, _d);                                                        \
    gload_lds16(_s + 32, _d + 1024);                                            \
  } while (0)

#define STG_A0(ss, kt) STG(Ab, LDA, 0, ss, ((w & 3) | ((w & 4) << 1)), kt)
#define STG_B0(ss, kt) STG(Bb, LDB, 1, ss, ((w & 1) | ((w & 6) << 1)), kt)
#define STG_A1(ss, kt) STG(Ab, LDA, 0, ss, (((w & 3) | ((w & 4) << 1)) + 4), kt)
#define STG_B1(ss, kt) STG(Bb, LDB, 1, ss, (((w & 1) | ((w & 6) << 1)) + 2), kt)

#define RD_A(dst, s, QM)                                                          \
  _Pragma("unroll") for (int mi = 0; mi < 4; ++mi)                                \
  _Pragma("unroll") for (int ks = 0; ks < 2; ++ks)                                \
    dst[mi][ks] = *(const short8*)(smem + (s) * 65536 +                           \
                    ((wm * 8 + (QM) * 4 + mi) * 2 + ks) * 1024 + fbase);

#define RD_B(dst, s, QN)                                                          \
  _Pragma("unroll") for (int ni = 0; ni < 2; ++ni)                                \
  _Pragma("unroll") for (int ks = 0; ks < 2; ++ks)                                \
    dst[ni][ks] = *(const short8*)(smem + (s) * 65536 + 32768 +                   \
                    ((wn * 4 + (QN) * 2 + ni) * 2 + ks) * 1024 + fbase);

#define MM(FA, FB, QM, QN)                                                        \
  _Pragma("unroll") for (int mi = 0; mi < 4; ++mi)                                \
  _Pragma("unroll") for (int ni = 0; ni < 2; ++ni)                                \
  _Pragma("unroll") for (int ks = 0; ks < 2; ++ks)                                \
    acc[(QM)*4+mi][(QN)*2+ni] = __builtin_amdgcn_mfma_f32_16x16x32_bf16(          \
        FA[mi][ks], FB[ni][ks], acc[(QM)*4+mi][(QN)*2+ni], 0, 0, 0);

template<int MODE>
__global__ __launch_bounds__(512)
void gemm256(const u16* __restrict__ A, const u16* __restrict__ Bq,
             u16* __restrict__ Oq, int NT)
{
  extern __shared__ char smem[];
  const int tid = threadIdx.x;
  const int l = tid & 63;
  const int w = tid >> 6;
  const int wm = w >> 2, wn = w & 3;

  constexpr int LDA = TP;
  constexpr int LDB = TP;

  // T1: bijective XCD swizzle (m204) over the flattened grid
  const int nwg = gridDim.x * gridDim.y;
  const int lin = blockIdx.y * gridDim.x + blockIdx.x;
  const int qq = nwg >> 3, rr = nwg & 7;
  const int xcd = lin & 7, idx = lin >> 3;
  const int wg = (xcd < rr ? xcd * (qq + 1) : rr * (qq + 1) + (xcd - rr) * qq) + idx;
  const int tn = wg % gridDim.x;
  const int tmz = wg / gridDim.x;   // batch z (MODE 2)

  const u16* Ab = A + (size_t)tmz * NN * TP;            // P batch base (256 rows)
  const u16* Bb = Bq + ((size_t)tmz * DD + tn * 256) * TP;  // Vt batch base + d-panel

  const int jj = (l < 32) ? l : (l ^ 2);
  const int srow = jj >> 2;
  const int scol = (jj & 3) * 8;
  const int fbase = (((l & 15) * 64) + ((l >> 4) * 16)) ^ (((l >> 3) & 1) << 5);

  f32x4 acc[8][4];
  #pragma unroll
  for (int i = 0; i < 8; ++i)
    #pragma unroll
    for (int jx = 0; jx < 4; ++jx) acc[i][jx] = (f32x4){0.f, 0.f, 0.f, 0.f};

  short8 fa0[4][2], fa1[4][2], fb0[2][2], fb1[2][2];

  STG_A0(0, 0); STG_B0(0, 0); STG_A1(0, 0); STG_B1(0, 0);
  VMW0(); BAR(); CFENCE();
  RD_A(fa0, 0, 0); RD_B(fb0, 0, 0);

  for (int g = 0; g < NT; ++g) {
    const int s = g & 1, ss = s ^ 1;
    const int st = (g + 1 < NT) ? (g + 1) : (NT - 1);

    VM2(); BAR(); CFENCE();
    RD_A(fa1, s, 1);
    STG_A0(ss, st);
    __builtin_amdgcn_s_setprio(1); MM(fa0, fb0, 0, 0); __builtin_amdgcn_s_setprio(0);

    VM2(); BAR(); CFENCE();
    RD_B(fb1, s, 1);
    STG_B0(ss, st);
    __builtin_amdgcn_s_setprio(1); MM(fa1, fb0, 1, 0); __builtin_amdgcn_s_setprio(0);

    STG_A1(ss, st);
    __builtin_amdgcn_s_setprio(1); MM(fa0, fb1, 0, 1); __builtin_amdgcn_s_setprio(0);

    VM2(); BAR(); CFENCE();
    RD_A(fa0, ss, 0); RD_B(fb0, ss, 0);
    STG_B1(ss, st);
    __builtin_amdgcn_s_setprio(1); MM(fa1, fb1, 1, 1); __builtin_amdgcn_s_setprio(0);
  }

  const int fr = l & 15, fro = (l >> 4) * 4;
  const int cb = tn * 256 + wn * 64;
  const size_t rb = (size_t)tmz * NN + wm * 128;
  #pragma unroll
  for (int MI = 0; MI < 8; ++MI)
    #pragma unroll
    for (int NI = 0; NI < 4; ++NI) {
      const int col = cb + NI * 16 + fr;
      #pragma unroll
      for (int r = 0; r < 4; ++r)
        Oq[(rb + MI * 16 + fro + r) * DD + col] = f2bf(acc[MI][NI][r]);
    }
}

// ========== shared 128x128 pipelined skeleton macros (validated as gemm_s, round 13) ==========

#define SSTG_A(ss, rg, kt) do {                                                  \
    const u16* _s = Abase + (size_t)((rg) * 16 + srow) * DD + (kt) * 64 + scol;  \
    char* _d = smem_s + (ss) * 32768 + (rg) * 2048;                              \
    gload_lds16(_s, _d);                                                         \
    gload_lds16(_s + 32, _d + 1024);                                             \
  } while (0)

#define SSTG_B(ss, rg, kt) do {                                                  \
    const int t_ = tn * 128 + (rg) * 16 + srow;                                  \
    const int rr_ = (t_ < NN) ? (z * NN + t_)                                    \
                  : ((t_ < TT) ? (BB * NN + t_ - NN) : BB * NN);                 \
    const u16* _s = Bm + (size_t)rr_ * DD + (kt) * 64 + scol;                    \
    char* _d = smem_s + (ss) * 32768 + 16384 + (rg) * 2048;                      \
    gload_lds16(_s, _d);                                                         \
    gload_lds16(_s + 32, _d + 1024);                                             \
  } while (0)

#define XSTG_B(ss, rg, kt) do {                                                  \
    const u16* _s = Bbase + (size_t)((rg) * 16 + srow) * DD + (kt) * 64 + scol;  \
    char* _d = smem_s + (ss) * 32768 + 16384 + (rg) * 2048;                      \
    gload_lds16(_s, _d);                                                         \
    gload_lds16(_s + 32, _d + 1024);                                             \
  } while (0)

#define SRD_A(dst, s, QM)                                                         \
  _Pragma("unroll") for (int mi = 0; mi < 2; ++mi)                                \
  _Pragma("unroll") for (int ks = 0; ks < 2; ++ks)                                \
    dst[mi][ks] = *(const short8*)(smem_s + (s) * 32768 +                         \
                    ((wm * 4 + (QM) * 2 + mi) * 2 + ks) * 1024 + fbase);

#define SRD_B(dst, s, QN)                                                         \
  _Pragma("unroll") for (int ni = 0; ni < 2; ++ni)                                \
  _Pragma("unroll") for (int ks = 0; ks < 2; ++ks)                                \
    dst[ni][ks] = *(const short8*)(smem_s + (s) * 32768 + 16384 +                 \
                    ((wn * 4 + (QN) * 2 + ni) * 2 + ks) * 1024 + fbase);

#define SMM(FA, FB, QM, QN)                                                       \
  _Pragma("unroll") for (int mi = 0; mi < 2; ++mi)                                \
  _Pragma("unroll") for (int ni = 0; ni < 2; ++ni)                                \
  _Pragma("unroll") for (int ks = 0; ks < 2; ++ks)                                \
    acc[(QM)*2+mi][(QN)*2+ni] = __builtin_amdgcn_mfma_f32_16x16x32_bf16(          \
        FA[mi][ks], FB[ni][ks], acc[(QM)*2+mi][(QN)*2+ni], 0, 0, 0);

#define SKEL_PIPELINE(STGB)                                                       \
  SSTG_A(0, rg0, 0); STGB(0, rg0, 0); SSTG_A(0, rg0 + 2, 0); STGB(0, rg0 + 2, 0); \
  VMW0(); BAR(); CFENCE();                                                        \
  SRD_A(fa0, 0, 0); SRD_B(fb0, 0, 0);                                             \
  for (int g = 0; g < 12; ++g) {                                                  \
    const int s = g & 1, ss = s ^ 1;                                              \
    const int st = (g + 1 < 12) ? (g + 1) : 11;                                   \
    VM2(); BAR(); CFENCE();                                                       \
    SRD_A(fa1, s, 1);                                                             \
    SSTG_A(ss, rg0, st);                                                          \
    __builtin_amdgcn_s_setprio(1); SMM(fa0, fb0, 0, 0); __builtin_amdgcn_s_setprio(0); \
    VM2(); BAR(); CFENCE();                                                       \
    SRD_B(fb1, s, 1);                                                             \
    STGB(ss, rg0, st);                                                            \
    __builtin_amdgcn_s_setprio(1); SMM(fa1, fb0, 1, 0); __builtin_amdgcn_s_setprio(0); \
    SSTG_A(ss, rg0 + 2, st);                                                      \
    __builtin_amdgcn_s_setprio(1); SMM(fa0, fb1, 0, 1); __builtin_amdgcn_s_setprio(0); \
    VM2(); BAR(); CFENCE();                                                       \
    SRD_A(fa0, ss, 0); SRD_B(fb0, ss, 0);                                         \
    STGB(ss, rg0 + 2, st);                                                        \
    __builtin_amdgcn_s_setprio(1); SMM(fa1, fb1, 1, 1); __builtin_amdgcn_s_setprio(0); \
  }

// ---------------- pipelined 128x128 B^T GEMM for S = Q K^T * scale (validated round 13) ----------------

__global__ __launch_bounds__(256)
void gemm_s(const u16* __restrict__ A, const u16* __restrict__ Bm,
            u16* __restrict__ F0)
{
  __shared__ char smem_s[65536];
  const int tid = threadIdx.x;
  const int l  = tid & 63;
  const int w  = tid >> 6;
  const int wm = w >> 1, wn = w & 1;
  const int tm = blockIdx.x, tn = blockIdx.y, z = blockIdx.z;

  const u16* Abase = A + ((size_t)z * NN + tm * 128) * DD;

  const int jj = (l < 32) ? l : (l ^ 2);
  const int srow = jj >> 2;
  const int scol = (jj & 3) * 8;
  const int fbase = (((l & 15) * 64) + ((l >> 4) * 16)) ^ (((l >> 3) & 1) << 5);
  const int rg0 = (w & 1) | ((w & 2) << 1);

  f32x4 acc[4][4];
  #pragma unroll
  for (int i = 0; i < 4; i++)
    #pragma unroll
    for (int j = 0; j < 4; j++) acc[i][j] = (f32x4){0.f, 0.f, 0.f, 0.f};

  short8 fa0[2][2], fa1[2][2], fb0[2][2], fb1[2][2];

  SKEL_PIPELINE(SSTG_B)

  const int fr  = l & 15;
  const int fro = (l >> 4) * 4;
  const float scl = 0.03608439182435161f;  // 768^-0.5
  u16* Sb = F0 + (size_t)z * NN * SP;
  const int cb = tn * 128 + wn * 64;
  const int rb = tm * 128 + wm * 64;
  #pragma unroll
  for (int mi = 0; mi < 4; mi++)
    #pragma unroll
    for (int ni = 0; ni < 4; ni++)
      #pragma unroll
      for (int r = 0; r < 4; r++)
        Sb[(size_t)(rb + mi * 16 + fro + r) * SP + cb + ni * 16 + fr] = f2bf(acc[mi][ni][r] * scl);
}

// ---------------- pipelined 128x128 B^T GEMM for G1 (MODE 0) and G3 (MODE 1) ----------------
// Round-14: gemm_s skeleton (BK=64, 64 KB LDS -> 2 blocks/CU, 4 waves, 64x64/wave,
// round-9 rotation) applied to the projection GEMMs. Mechanism: 2 blocks/CU fills
// barrier/VM-wait stalls that convoyed the single-block 256^2 version (36% MfmaUtil).
// Flattened grid + m204 XCD swizzle (tn fastest) keeps each A-panel's tn-consumers
// on one XCD. K-accumulation order identical to gemm256 -> bitwise-same outputs.
// MODE 0: A=Ab[33024], NTN=18, B = Wq/Wk/Wv^T by tn/6, +bias -> bf16 Q/K/V.
// MODE 1: A=O[32768],  NTN=6,  B = Wot, +bias -> fp32 out.

template<int MODE>
__global__ __launch_bounds__(256)
void gemm128(const u16* __restrict__ A, const u16* __restrict__ Bq,
             const u16* __restrict__ Bk, const u16* __restrict__ Bv,
             const float* __restrict__ b0, const float* __restrict__ b1,
             const float* __restrict__ b2,
             u16* __restrict__ Oq, u16* __restrict__ Ok, u16* __restrict__ Ov,
             float* __restrict__ FO, int NTN)
{
  __shared__ char smem_s[65536];
  const int tid = threadIdx.x;
  const int l  = tid & 63;
  const int w  = tid >> 6;
  const int wm = w >> 1, wn = w & 1;

  // m204 bijective XCD swizzle over flattened 1-D grid; tn fastest within chunk
  const int nwg = gridDim.x;
  const int lin = blockIdx.x;
  const int qq = nwg >> 3, rr = nwg & 7;
  const int xcd = lin & 7, idx = lin >> 3;
  const int wg = (xcd < rr ? xcd * (qq + 1) : rr * (qq + 1) + (xcd - rr) * qq) + idx;
  const int tn = wg % NTN;
  const int tm = wg / NTN;

  const u16* Abase = A + (size_t)tm * 128 * DD;
  const u16* Bbase;
  int matsel = 0;
  if constexpr (MODE == 0) {
    matsel = tn / 6;
    const u16* Wp = (matsel == 0) ? Bq : (matsel == 1) ? Bk : Bv;
    Bbase = Wp + (size_t)(tn % 6) * 128 * DD;
  } else {
    Bbase = Bq + (size_t)tn * 128 * DD;
  }

  const int jj = (l < 32) ? l : (l ^ 2);
  const int srow = jj >> 2;
  const int scol = (jj & 3) * 8;
  const int fbase = (((l & 15) * 64) + ((l >> 4) * 16)) ^ (((l >> 3) & 1) << 5);
  const int rg0 = (w & 1) | ((w & 2) << 1);

  f32x4 acc[4][4];
  #pragma unroll
  for (int i = 0; i < 4; i++)
    #pragma unroll
    for (int j = 0; j < 4; j++) acc[i][j] = (f32x4){0.f, 0.f, 0.f, 0.f};

  short8 fa0[2][2], fa1[2][2], fb0[2][2], fb1[2][2];

  SKEL_PIPELINE(XSTG_B)

  const int fr  = l & 15;
  const int fro = (l >> 4) * 4;
  if constexpr (MODE == 0) {
    const float* bias = (matsel == 0) ? b0 : (matsel == 1) ? b1 : b2;
    u16* ob = (matsel == 0) ? Oq : (matsel == 1) ? Ok : Ov;
    const int cb = (tn % 6) * 128 + wn * 64;
    const size_t rb = (size_t)tm * 128 + wm * 64;
    #pragma unroll
    for (int mi = 0; mi < 4; mi++)
      #pragma unroll
      for (int ni = 0; ni < 4; ni++) {
        const int col = cb + ni * 16 + fr;
        const float bvv = bias[col];
        #pragma unroll
        for (int r = 0; r < 4; r++)
          ob[(rb + mi * 16 + fro + r) * DD + col] = f2bf(acc[mi][ni][r] + bvv);
      }
  } else {
    const int cb = tn * 128 + wn * 64;
    const size_t rb = (size_t)tm * 128 + wm * 64;
    #pragma unroll
    for (int mi = 0; mi < 4; mi++)
      #pragma unroll
      for (int ni = 0; ni < 4; ni++) {
        const int col = cb + ni * 16 + fr;
        const float bvv = b0[col];
        #pragma unroll
        for (int r = 0; r < 4; r++)
          FO[(rb + mi * 16 + fro + r) * DD + col] = acc[mi][ni][r] + bvv;
      }
  }
}

// ---------------- softmax: one wave per row of S[32768][384] (bf16), cols 0..263 valid ----------------

__global__ __launch_bounds__(256)
void softmax_k(const u16* __restrict__ S, u16* __restrict__ P) {
  const int l = threadIdx.x & 63;
  const int row = blockIdx.x * 4 + (threadIdx.x >> 6);
  const u16* s = S + (size_t)row * SP;
  float v0 = bf2f(s[l]), v1 = bf2f(s[64 + l]), v2 = bf2f(s[128 + l]), v3 = bf2f(s[192 + l]);
  float v4 = (l < 8) ? bf2f(s[256 + l]) : -__builtin_inff();
  float m = fmaxf(fmaxf(fmaxf(v0, v1), fmaxf(v2, v3)), v4);
  #pragma unroll
  for (int off = 32; off; off >>= 1) m = fmaxf(m, __shfl_xor(m, off));
  float e0 = __expf(v0 - m), e1 = __expf(v1 - m), e2 = __expf(v2 - m), e3 = __expf(v3 - m);
  float e4 = (l < 8) ? __expf(v4 - m) : 0.f;
  float sum = e0 + e1 + e2 + e3 + e4;
  #pragma unroll
  for (int off = 32; off; off >>= 1) sum += __shfl_xor(sum, off);
  const float inv = 1.f / sum;
  u16* p = P + (size_t)row * TP;
  p[l] = f2bf(e0 * inv); p[64 + l] = f2bf(e1 * inv);
  p[128 + l] = f2bf(e2 * inv); p[192 + l] = f2bf(e3 * inv);
  if (l < 8) p[256 + l] = f2bf(e4 * inv);
  else       p[256 + l] = 0;            // zero pad cols 264..319
}

// ---------------- V transpose: Vt[b][d][t] (t padded to 320 with zeros) ----------------

__global__ __launch_bounds__(256)
void transpose_v(const u16* __restrict__ V, u16* __restrict__ Vt) {
  __shared__ u16 ls[64 * 66];
  const int b = blockIdx.z;
  const int d0 = blockIdx.x * 64;
  const int t0 = blockIdx.y * 64;
  const int tid = threadIdx.x;
  #pragma unroll
  for (int q = 0; q < 2; ++q) {
    const int idx = q * 256 + tid;
    const int tr = idx >> 3;
    const int dg = (idx & 7) * 8;
    const int t = t0 + tr;
    short8 v = (short8)(short)0;
    if (t < NN)       v = *(const short8*)(V + ((size_t)b * NN + t) * DD + d0 + dg);
    else if (t < TT)  v = *(const short8*)(V + (size_t)(BB * NN + t - NN) * DD + d0 + dg);
    #pragma unroll
    for (int e = 0; e < 8; ++e) ls[tr * 66 + dg + e] = (u16)v[e];
  }
  __syncthreads();
  #pragma unroll
  for (int q = 0; q < 2; ++q) {
    const int idx = q * 256 + tid;
    const int dr = idx >> 3;
    const int tg = (idx & 7) * 8;
    short8 v;
    #pragma unroll
    for (int e = 0; e < 8; ++e) v[e] = (short)ls[(tg + e) * 66 + dr];
    *(short8*)(Vt + ((size_t)b * DD + d0 + dr) * TP + t0 + tg) = v;
  }
}

// ---------------- launch ----------------
// Order: conv_x, conv_w -> G1(128^2) -> G2a(S bf16) -> softmax -> transpose_v -> G2c -> G3(128^2).
// d_out (100.66 MB): Ab [0,50.72M) live conv_x->G1; S (bf16) [0,25.2M) live
//   G2a->softmax; P [50.72M,71.70M) live softmax->G2c; W^T(q,k,v) [97.12M,100.66M)
//   live conv_w->G1.  All dead before G3 overwrites d_out.
// ws (high-water 153.35 MB, proven): Qb@0, Kb@50.72M (live G1->G2a);
//   Vb@101.45M (live G1->transpose_v); Vt@0 (62.91M over dead Qb+Kb-head,
//   live transpose_v->G2c); O@62.91M (50.33M over dead Kb-tail+Vb-head,
//   live G2c->G3); Wot@152.17M (live conv_w->G3).

extern "C" void kernel_launch(void* const* d_in, const int* in_sizes, int n_in,
                              void* d_out, int out_size, void* d_ws, size_t ws_size,
                              hipStream_t stream) {
  const float* x   = (const float*)d_in[0];
  const float* mem = (const float*)d_in[1];
  const float* Wq  = (const float*)d_in[2];
  const float* bq  = (const float*)d_in[3];
  const float* Wk  = (const float*)d_in[4];
  const float* bk  = (const float*)d_in[5];
  const float* Wv  = (const float*)d_in[6];
  const float* bv  = (const float*)d_in[7];
  const float* Wo  = (const float*)d_in[8];
  const float* bo  = (const float*)d_in[9];
  float* out = (float*)d_out;
  (void)ws_size; (void)in_sizes; (void)n_in; (void)out_size;

  const size_t QKV_B = (size_t)AROWS2 * DD * 2;        // 50,724,864
  char* wsb = (char*)d_ws;
  u16* Qb  = (u16*)(wsb);
  u16* Kb  = (u16*)(wsb + QKV_B);
  u16* Vb  = (u16*)(wsb + 2 * QKV_B);
  u16* Vt  = (u16*)(wsb);                              // over dead Qb+Kb head
  u16* O   = (u16*)(wsb + (size_t)BB * DD * TP * 2);   // @62,914,560
  u16* Wot = (u16*)(wsb + 3 * QKV_B);                  // @152,174,592

  u16*   Ab  = (u16*)d_out;                            // live conv_x -> G1
  u16*   S   = (u16*)d_out;                            // live G2a -> softmax (bf16)
  u16*   P   = (u16*)((char*)d_out + QKV_B);           // live softmax -> G2c
  u16*   Wqt = (u16*)((char*)d_out + 97124352);        // live conv_w -> G1
  u16*   Wkt = Wqt + (size_t)DD * DD;
  u16*   Wvt = Wkt + (size_t)DD * DD;

  conv_x<<<2048, 256, 0, stream>>>(x, mem, Ab);
  conv_w<<<1024, 256, 0, stream>>>(Wq, Wk, Wv, Wo, Wqt, Wkt, Wvt, Wot);

  // G1: QKV projection  [33024 x 2304] = Ab @ [Wqt|Wkt|Wvt]^T  (+bias, -> bf16)
  // 128^2 pipelined, 2 blocks/CU; grid 258*18 = 4644 flattened
  gemm128<0><<<4644, 256, 0, stream>>>(
      Ab, Wqt, Wkt, Wvt, bq, bk, bv, Qb, Kb, Vb, nullptr, 18);

  // G2a: S = Q @ K^T * scale  (per batch, K-rows remapped, pipelined, bf16 out)
  gemm_s<<<dim3(2, 3, BB), 256, 0, stream>>>(Qb, Kb, S);

  // softmax rows -> P (bf16, zero-padded to 320 cols)
  softmax_k<<<8192, 256, 0, stream>>>(S, P);

  // Vt[b][d][t]  (writes over dead Qb/Kb region)
  transpose_v<<<dim3(12, 5, BB), 256, 0, stream>>>(Vb, Vt);

  // G2c: O = P @ Vt^T per batch (pipelined 256-tile, K=320)
  gemm256<2><<<dim3(3, 128), 512, 131072, stream>>>(P, Vt, O, 5);

  // G3: out = O @ Wot^T + bo  (fp32)  -- 128^2 pipelined; grid 256*6 = 1536
  gemm128<1><<<1536, 256, 0, stream>>>(
      O, Wot, nullptr, nullptr, bo, nullptr, nullptr,
      nullptr, nullptr, nullptr, out, 6);
}

// Round 15
// 325.535 us; speedup vs baseline: 1.0191x; 1.0191x over previous
//
#include <hip/hip_runtime.h>
#include <hip/hip_bf16.h>

typedef __attribute__((ext_vector_type(4))) float f32x4;
typedef __attribute__((ext_vector_type(8))) short short8;
typedef __attribute__((ext_vector_type(4))) unsigned short us4;
typedef unsigned short u16;

#define DEVI __device__ __forceinline__

#define BB 128      // batches
#define NN 256      // input patches per batch
#define MMEM 8      // memory tokens
#define DD 768      // embed dim
#define TT 264      // N + M
#define TP 320      // P/Vt col padding (zeros in cols 264..319)
#define SP 384      // S col padding (3 x 128 tiles)
#define AROWS2 33024  // 129*256: rows for the 256-tile GEMMs (x .. memory .. zero pad)

DEVI u16 f2bf(float f) {
  __hip_bfloat16 b = __float2bfloat16(f);
  u16 u; __builtin_memcpy(&u, &b, 2); return u;
}

DEVI float bf2f(u16 u) {
  unsigned int v = ((unsigned int)u) << 16;
  float f; __builtin_memcpy(&f, &v, 4); return f;
}

DEVI void gload_lds16(const void* g, void* l) {
  __builtin_amdgcn_global_load_lds((const __attribute__((address_space(1))) void*)g,
                                   (__attribute__((address_space(3))) void*)l, 16, 0, 0);
}

// ---------------- conversion kernels ----------------

__global__ __launch_bounds__(256)
void conv_x(const float* __restrict__ x, const float* __restrict__ mem, u16* __restrict__ Ab) {
  const long total4 = (long)AROWS2 * DD / 4;
  for (long i = (long)blockIdx.x * blockDim.x + threadIdx.x; i < total4;
       i += (long)gridDim.x * blockDim.x) {
    long e = i * 4;
    int row = (int)(e / DD);
    int cb  = (int)(e % DD);
    f32x4 v = {0.f, 0.f, 0.f, 0.f};
    if (row < BB * NN)             v = *(const f32x4*)(x   + (size_t)row * DD + cb);
    else if (row < BB * NN + MMEM) v = *(const f32x4*)(mem + (size_t)(row - BB * NN) * DD + cb);
    us4 o = {f2bf(v[0]), f2bf(v[1]), f2bf(v[2]), f2bf(v[3])};
    *(us4*)(Ab + e) = o;
  }
}

__global__ __launch_bounds__(256)
void conv_w(const float* __restrict__ Wq, const float* __restrict__ Wk,
            const float* __restrict__ Wv, const float* __restrict__ Wo,
            u16* __restrict__ Wqt, u16* __restrict__ Wkt,
            u16* __restrict__ Wvt, u16* __restrict__ Wot) {
  const int total = 4 * DD * DD;
  for (int i = blockIdx.x * blockDim.x + threadIdx.x; i < total;
       i += gridDim.x * blockDim.x) {
    int mat = i / (DD * DD), rem = i % (DD * DD);
    int j = rem / DD, d = rem % DD;
    const float* W = (mat == 0) ? Wq : (mat == 1) ? Wk : (mat == 2) ? Wv : Wo;
    u16* Wt = (mat == 0) ? Wqt : (mat == 1) ? Wkt : (mat == 2) ? Wvt : Wot;
    Wt[(size_t)j * DD + d] = f2bf(W[(size_t)d * DD + j]);
  }
}

// ================= 256x256 8-wave pipelined B^T GEMM (round-9 loop, proven) =================
// MODE 0: QKV projection.  MODE 1: out = A @ B^T + bias (fp32).  MODE 2: O = P @ Vt^T per batch.

#define BAR()    __builtin_amdgcn_s_barrier()
#define CFENCE() asm volatile("" ::: "memory")
#define VM2()    asm volatile("s_waitcnt vmcnt(2)" ::: "memory")
#define VMW0()   asm volatile("s_waitcnt vmcnt(0)" ::: "memory")

#define STG(gb, ld, isB, ss, rg, kt) do {                                       \
    const u16* _s = (gb) + (size_t)((rg) * 16 + srow) * (ld) + (kt) * 64 + scol;\
    char* _d = smem + (ss) * 65536 + (isB) * 32768 + (rg) * 2048;               \
    gload_lds16(_s, _d);                                                        \
    gload_lds16(_s + 32, _d + 1024);                                            \
  } while (0)

#define STG_A0(ss, kt) STG(Ab, LDA, 0, ss, ((w & 3) | ((w & 4) << 1)), kt)
#define STG_B0(ss, kt) STG(Bb, LDB, 1, ss, ((w & 1) | ((w & 6) << 1)), kt)
#define STG_A1(ss, kt) STG(Ab, LDA, 0, ss, (((w & 3) | ((w & 4) << 1)) + 4), kt)
#define STG_B1(ss, kt) STG(Bb, LDB, 1, ss, (((w & 1) | ((w & 6) << 1)) + 2), kt)

#define RD_A(dst, s, QM)                                                          \
  _Pragma("unroll") for (int mi = 0; mi < 4; ++mi)                                \
  _Pragma("unroll") for (int ks = 0; ks < 2; ++ks)                                \
    dst[mi][ks] = *(const short8*)(smem + (s) * 65536 +                           \
                    ((wm * 8 + (QM) * 4 + mi) * 2 + ks) * 1024 + fbase);

#define RD_B(dst, s, QN)                                                          \
  _Pragma("unroll") for (int ni = 0; ni < 2; ++ni)                                \
  _Pragma("unroll") for (int ks = 0; ks < 2; ++ks)                                \
    dst[ni][ks] = *(const short8*)(smem + (s) * 65536 + 32768 +                   \
                    ((wn * 4 + (QN) * 2 + ni) * 2 + ks) * 1024 + fbase);

#define MM(FA, FB, QM, QN)                                                        \
  _Pragma("unroll") for (int mi = 0; mi < 4; ++mi)                                \
  _Pragma("unroll") for (int ni = 0; ni < 2; ++ni)                                \
  _Pragma("unroll") for (int ks = 0; ks < 2; ++ks)                                \
    acc[(QM)*4+mi][(QN)*2+ni] = __builtin_amdgcn_mfma_f32_16x16x32_bf16(          \
        FA[mi][ks], FB[ni][ks], acc[(QM)*4+mi][(QN)*2+ni], 0, 0, 0);

template<int MODE>
__global__ __launch_bounds__(512)
void gemm256(const u16* __restrict__ A, const u16* __restrict__ Bq,
             const u16* __restrict__ Bk, const u16* __restrict__ Bv,
             const float* __restrict__ b0, const float* __restrict__ b1,
             const float* __restrict__ b2,
             u16* __restrict__ Oq, u16* __restrict__ Ok, u16* __restrict__ Ov,
             float* __restrict__ FO, int NT)
{
  extern __shared__ char smem[];
  const int tid = threadIdx.x;
  const int l = tid & 63;
  const int w = tid >> 6;
  const int wm = w >> 2, wn = w & 3;

  constexpr int LDA = (MODE == 2) ? TP : DD;
  constexpr int LDB = (MODE == 2) ? TP : DD;

  // T1: bijective XCD swizzle (m204) over the flattened grid
  const int nwg = gridDim.x * gridDim.y;
  const int lin = blockIdx.y * gridDim.x + blockIdx.x;
  const int qq = nwg >> 3, rr = nwg & 7;
  const int xcd = lin & 7, idx = lin >> 3;
  const int wg = (xcd < rr ? xcd * (qq + 1) : rr * (qq + 1) + (xcd - rr) * qq) + idx;
  const int tn = wg % gridDim.x;
  const int tmz = wg / gridDim.x;   // tm (MODE 0/1) or batch z (MODE 2)

  const u16* Ab; const u16* Bb;
  int matsel = 0;
  if constexpr (MODE == 0) {
    Ab = A + (size_t)tmz * 256 * DD;
    matsel = tn / 3;
    const u16* Wp = (matsel == 0) ? Bq : (matsel == 1) ? Bk : Bv;
    Bb = Wp + (size_t)(tn % 3) * 256 * DD;
  } else if constexpr (MODE == 1) {
    Ab = A + (size_t)tmz * 256 * DD;
    Bb = Bq + (size_t)tn * 256 * DD;
  } else {
    Ab = A + (size_t)tmz * NN * TP;                      // P batch base (256 rows)
    Bb = Bq + ((size_t)tmz * DD + tn * 256) * TP;        // Vt batch base + d-panel
  }

  const int jj = (l < 32) ? l : (l ^ 2);
  const int srow = jj >> 2;
  const int scol = (jj & 3) * 8;
  const int fbase = (((l & 15) * 64) + ((l >> 4) * 16)) ^ (((l >> 3) & 1) << 5);

  f32x4 acc[8][4];
  #pragma unroll
  for (int i = 0; i < 8; ++i)
    #pragma unroll
    for (int jx = 0; jx < 4; ++jx) acc[i][jx] = (f32x4){0.f, 0.f, 0.f, 0.f};

  short8 fa0[4][2], fa1[4][2], fb0[2][2], fb1[2][2];

  // prologue: stage K-tile 0 -> slot 0; drain; read ph0 fragments
  STG_A0(0, 0); STG_B0(0, 0); STG_A1(0, 0); STG_B1(0, 0);
  VMW0(); BAR(); CFENCE();
  RD_A(fa0, 0, 0); RD_B(fb0, 0, 0);

  for (int g = 0; g < NT; ++g) {
    const int s = g & 1, ss = s ^ 1;
    const int st = (g + 1 < NT) ? (g + 1) : (NT - 1);  // last iter re-stages (dead)

    // ph0: MM Q00 | RD fa1 (slot s) | stage A0(g+1)
    VM2(); BAR(); CFENCE();
    RD_A(fa1, s, 1);
    STG_A0(ss, st);
    __builtin_amdgcn_s_setprio(1); MM(fa0, fb0, 0, 0); __builtin_amdgcn_s_setprio(0);

    // ph1: MM Q10 | RD fb1 (slot s) | stage B0(g+1)
    VM2(); BAR(); CFENCE();
    RD_B(fb1, s, 1);
    STG_B0(ss, st);
    __builtin_amdgcn_s_setprio(1); MM(fa1, fb0, 1, 0); __builtin_amdgcn_s_setprio(0);

    // ph2: MM Q01 | no reads, no barrier | stage A1(g+1)
    STG_A1(ss, st);
    __builtin_amdgcn_s_setprio(1); MM(fa0, fb1, 0, 1); __builtin_amdgcn_s_setprio(0);

    // ph3: MM Q11 | RD fa0,fb0 (slot ss = tile g+1) | stage B1(g+1)
    VM2(); BAR(); CFENCE();
    RD_A(fa0, ss, 0); RD_B(fb0, ss, 0);
    STG_B1(ss, st);
    __builtin_amdgcn_s_setprio(1); MM(fa1, fb1, 1, 1); __builtin_amdgcn_s_setprio(0);
  }

  const int fr = l & 15, fro = (l >> 4) * 4;
  if constexpr (MODE == 0) {
    const float* bias = (matsel == 0) ? b0 : (matsel == 1) ? b1 : b2;
    u16* ob = (matsel == 0) ? Oq : (matsel == 1) ? Ok : Ov;
    const int cb = (tn % 3) * 256 + wn * 64;
    const size_t rb = (size_t)tmz * 256 + wm * 128;
    #pragma unroll
    for (int MI = 0; MI < 8; ++MI)
      #pragma unroll
      for (int NI = 0; NI < 4; ++NI) {
        const int col = cb + NI * 16 + fr;
        const float bvv = bias[col];
        #pragma unroll
        for (int r = 0; r < 4; ++r)
          ob[(rb + MI * 16 + fro + r) * DD + col] = f2bf(acc[MI][NI][r] + bvv);
      }
  } else if constexpr (MODE == 1) {
    const int cb = tn * 256 + wn * 64;
    const size_t rb = (size_t)tmz * 256 + wm * 128;
    #pragma unroll
    for (int MI = 0; MI < 8; ++MI)
      #pragma unroll
      for (int NI = 0; NI < 4; ++NI) {
        const int col = cb + NI * 16 + fr;
        const float bvv = b0[col];
        #pragma unroll
        for (int r = 0; r < 4; ++r)
          FO[(rb + MI * 16 + fro + r) * DD + col] = acc[MI][NI][r] + bvv;
      }
  } else {
    const int cb = tn * 256 + wn * 64;
    const size_t rb = (size_t)tmz * NN + wm * 128;
    #pragma unroll
    for (int MI = 0; MI < 8; ++MI)
      #pragma unroll
      for (int NI = 0; NI < 4; ++NI) {
        const int col = cb + NI * 16 + fr;
        #pragma unroll
        for (int r = 0; r < 4; ++r)
          Oq[(rb + MI * 16 + fro + r) * DD + col] = f2bf(acc[MI][NI][r]);
      }
  }
}

// ---------------- pipelined 128x128 B^T GEMM for S = Q K^T * scale (bf16 out) ----------------
// Round-9's 4-phase rotation applied to gemm_s. BK=64 (NT=12), 2 LDS slots
// of (A 16K + B 16K) = 64 KB static -> 2 blocks/CU. 4 waves, per-wave 64x64 output:
// quadrants 2x2 frags, 8 MFMA/phase. Stage-groups A0/B0 = {0,1,4,5}: ph0 VM2
// retires A1(g), ph1 retires B1(g), ph3 retires A0,B0(g+1).

#define SSTG_A(ss, rg, kt) do {                                                  \
    const u16* _s = Abase + (size_t)((rg) * 16 + srow) * DD + (kt) * 64 + scol;  \
    char* _d = smem_s + (ss) * 32768 + (rg) * 2048;                              \
    gload_lds16(_s, _d);                                                         \
    gload_lds16(_s + 32, _d + 1024);                                             \
  } while (0)

#define SSTG_B(ss, rg, kt) do {                                                  \
    const int t_ = tn * 128 + (rg) * 16 + srow;                                  \
    const int rr_ = (t_ < NN) ? (z * NN + t_)                                    \
                  : ((t_ < TT) ? (BB * NN + t_ - NN) : BB * NN);                 \
    const u16* _s = Bm + (size_t)rr_ * DD + (kt) * 64 + scol;                    \
    char* _d = smem_s + (ss) * 32768 + 16384 + (rg) * 2048;                      \
    gload_lds16(_s, _d);                                                         \
    gload_lds16(_s + 32, _d + 1024);                                             \
  } while (0)

#define SRD_A(dst, s, QM)                                                         \
  _Pragma("unroll") for (int mi = 0; mi < 2; ++mi)                                \
  _Pragma("unroll") for (int ks = 0; ks < 2; ++ks)                                \
    dst[mi][ks] = *(const short8*)(smem_s + (s) * 32768 +                         \
                    ((wm * 4 + (QM) * 2 + mi) * 2 + ks) * 1024 + fbase);

#define SRD_B(dst, s, QN)                                                         \
  _Pragma("unroll") for (int ni = 0; ni < 2; ++ni)                                \
  _Pragma("unroll") for (int ks = 0; ks < 2; ++ks)                                \
    dst[ni][ks] = *(const short8*)(smem_s + (s) * 32768 + 16384 +                 \
                    ((wn * 4 + (QN) * 2 + ni) * 2 + ks) * 1024 + fbase);

#define SMM(FA, FB, QM, QN)                                                       \
  _Pragma("unroll") for (int mi = 0; mi < 2; ++mi)                                \
  _Pragma("unroll") for (int ni = 0; ni < 2; ++ni)                                \
  _Pragma("unroll") for (int ks = 0; ks < 2; ++ks)                                \
    acc[(QM)*2+mi][(QN)*2+ni] = __builtin_amdgcn_mfma_f32_16x16x32_bf16(          \
        FA[mi][ks], FB[ni][ks], acc[(QM)*2+mi][(QN)*2+ni], 0, 0, 0);

__global__ __launch_bounds__(256)
void gemm_s(const u16* __restrict__ A, const u16* __restrict__ Bm,
            u16* __restrict__ F0)
{
  __shared__ char smem_s[65536];
  const int tid = threadIdx.x;
  const int l  = tid & 63;
  const int w  = tid >> 6;
  const int wm = w >> 1, wn = w & 1;
  const int tm = blockIdx.x, tn = blockIdx.y, z = blockIdx.z;

  const u16* Abase = A + ((size_t)z * NN + tm * 128) * DD;

  const int jj = (l < 32) ? l : (l ^ 2);
  const int srow = jj >> 2;
  const int scol = (jj & 3) * 8;
  const int fbase = (((l & 15) * 64) + ((l >> 4) * 16)) ^ (((l >> 3) & 1) << 5);

  // stage-group rgroups per wave: A0/B0 -> {0,1,4,5}[w]; A1/B1 -> +2
  const int rg0 = (w & 1) | ((w & 2) << 1);

  f32x4 acc[4][4];
  #pragma unroll
  for (int i = 0; i < 4; i++)
    #pragma unroll
    for (int j = 0; j < 4; j++) acc[i][j] = (f32x4){0.f, 0.f, 0.f, 0.f};

  short8 fa0[2][2], fa1[2][2], fb0[2][2], fb1[2][2];

  // prologue: stage K-tile 0 -> slot 0; drain; read ph0 fragments
  SSTG_A(0, rg0, 0); SSTG_B(0, rg0, 0); SSTG_A(0, rg0 + 2, 0); SSTG_B(0, rg0 + 2, 0);
  VMW0(); BAR(); CFENCE();
  SRD_A(fa0, 0, 0); SRD_B(fb0, 0, 0);

  for (int g = 0; g < 12; ++g) {
    const int s = g & 1, ss = s ^ 1;
    const int st = (g + 1 < 12) ? (g + 1) : 11;  // last iter re-stages (dead)

    // ph0: MM Q00 | RD fa1 (slot s) | stage A0(g+1)
    VM2(); BAR(); CFENCE();
    SRD_A(fa1, s, 1);
    SSTG_A(ss, rg0, st);
    __builtin_amdgcn_s_setprio(1); SMM(fa0, fb0, 0, 0); __builtin_amdgcn_s_setprio(0);

    // ph1: MM Q10 | RD fb1 (slot s) | stage B0(g+1)
    VM2(); BAR(); CFENCE();
    SRD_B(fb1, s, 1);
    SSTG_B(ss, rg0, st);
    __builtin_amdgcn_s_setprio(1); SMM(fa1, fb0, 1, 0); __builtin_amdgcn_s_setprio(0);

    // ph2: MM Q01 | no reads, no barrier | stage A1(g+1)
    SSTG_A(ss, rg0 + 2, st);
    __builtin_amdgcn_s_setprio(1); SMM(fa0, fb1, 0, 1); __builtin_amdgcn_s_setprio(0);

    // ph3: MM Q11 | RD fa0,fb0 (slot ss = tile g+1) | stage B1(g+1)
    VM2(); BAR(); CFENCE();
    SRD_A(fa0, ss, 0); SRD_B(fb0, ss, 0);
    SSTG_B(ss, rg0 + 2, st);
    __builtin_amdgcn_s_setprio(1); SMM(fa1, fb1, 1, 1); __builtin_amdgcn_s_setprio(0);
  }

  const int fr  = l & 15;
  const int fro = (l >> 4) * 4;
  const float scl = 0.03608439182435161f;  // 768^-0.5
  u16* Sb = F0 + (size_t)z * NN * SP;
  const int cb = tn * 128 + wn * 64;
  const int rb = tm * 128 + wm * 64;
  #pragma unroll
  for (int mi = 0; mi < 4; mi++)
    #pragma unroll
    for (int ni = 0; ni < 4; ni++)
      #pragma unroll
      for (int r = 0; r < 4; r++)
        Sb[(size_t)(rb + mi * 16 + fro + r) * SP + cb + ni * 16 + fr] = f2bf(acc[mi][ni][r] * scl);
}

// ---------------- softmax: one wave per row of S[32768][384] (bf16), cols 0..263 valid ----------------

__global__ __launch_bounds__(256)
void softmax_k(const u16* __restrict__ S, u16* __restrict__ P) {
  const int l = threadIdx.x & 63;
  const int row = blockIdx.x * 4 + (threadIdx.x >> 6);
  const u16* s = S + (size_t)row * SP;
  float v0 = bf2f(s[l]), v1 = bf2f(s[64 + l]), v2 = bf2f(s[128 + l]), v3 = bf2f(s[192 + l]);
  float v4 = (l < 8) ? bf2f(s[256 + l]) : -__builtin_inff();
  float m = fmaxf(fmaxf(fmaxf(v0, v1), fmaxf(v2, v3)), v4);
  #pragma unroll
  for (int off = 32; off; off >>= 1) m = fmaxf(m, __shfl_xor(m, off));
  float e0 = __expf(v0 - m), e1 = __expf(v1 - m), e2 = __expf(v2 - m), e3 = __expf(v3 - m);
  float e4 = (l < 8) ? __expf(v4 - m) : 0.f;
  float sum = e0 + e1 + e2 + e3 + e4;
  #pragma unroll
  for (int off = 32; off; off >>= 1) sum += __shfl_xor(sum, off);
  const float inv = 1.f / sum;
  u16* p = P + (size_t)row * TP;
  p[l] = f2bf(e0 * inv); p[64 + l] = f2bf(e1 * inv);
  p[128 + l] = f2bf(e2 * inv); p[192 + l] = f2bf(e3 * inv);
  if (l < 8) p[256 + l] = f2bf(e4 * inv);
  else       p[256 + l] = 0;            // zero pad cols 264..319
}

// ---------------- V transpose: Vt[b][d][t] (t padded to 320 with zeros) ----------------

__global__ __launch_bounds__(256)
void transpose_v(const u16* __restrict__ V, u16* __restrict__ Vt) {
  __shared__ u16 ls[64 * 66];
  const int b = blockIdx.z;
  const int d0 = blockIdx.x * 64;
  const int t0 = blockIdx.y * 64;
  const int tid = threadIdx.x;
  #pragma unroll
  for (int q = 0; q < 2; ++q) {
    const int idx = q * 256 + tid;
    const int tr = idx >> 3;
    const int dg = (idx & 7) * 8;
    const int t = t0 + tr;
    short8 v = (short8)(short)0;
    if (t < NN)       v = *(const short8*)(V + ((size_t)b * NN + t) * DD + d0 + dg);
    else if (t < TT)  v = *(const short8*)(V + (size_t)(BB * NN + t - NN) * DD + d0 + dg);
    #pragma unroll
    for (int e = 0; e < 8; ++e) ls[tr * 66 + dg + e] = (u16)v[e];
  }
  __syncthreads();
  #pragma unroll
  for (int q = 0; q < 2; ++q) {
    const int idx = q * 256 + tid;
    const int dr = idx >> 3;
    const int tg = (idx & 7) * 8;
    short8 v;
    #pragma unroll
    for (int e = 0; e < 8; ++e) v[e] = (short)ls[(tg + e) * 66 + dr];
    *(short8*)(Vt + ((size_t)b * DD + d0 + dr) * TP + t0 + tg) = v;
  }
}

// ---------------- launch ----------------
// Order: conv_x, conv_w -> G1 -> G2a(S bf16, pipelined) -> softmax -> transpose_v -> G2c -> G3.
// d_out (100.66 MB): Ab [0,50.72M) live conv_x->G1; S (bf16) [0,25.2M) live
//   G2a->softmax; P [50.72M,71.70M) live softmax->G2c; W^T(q,k,v) [97.12M,100.66M)
//   live conv_w->G1.  All dead before G3 overwrites d_out.
// ws (high-water 153.35 MB, proven): Qb@0, Kb@50.72M (live G1->G2a);
//   Vb@101.45M (live G1->transpose_v); Vt@0 (62.91M over dead Qb+Kb-head,
//   live transpose_v->G2c); O@62.91M (50.33M over dead Kb-tail+Vb-head,
//   live G2c->G3); Wot@152.17M (live conv_w->G3).

extern "C" void kernel_launch(void* const* d_in, const int* in_sizes, int n_in,
                              void* d_out, int out_size, void* d_ws, size_t ws_size,
                              hipStream_t stream) {
  const float* x   = (const float*)d_in[0];
  const float* mem = (const float*)d_in[1];
  const float* Wq  = (const float*)d_in[2];
  const float* bq  = (const float*)d_in[3];
  const float* Wk  = (const float*)d_in[4];
  const float* bk  = (const float*)d_in[5];
  const float* Wv  = (const float*)d_in[6];
  const float* bv  = (const float*)d_in[7];
  const float* Wo  = (const float*)d_in[8];
  const float* bo  = (const float*)d_in[9];
  float* out = (float*)d_out;
  (void)ws_size; (void)in_sizes; (void)n_in; (void)out_size;

  const size_t QKV_B = (size_t)AROWS2 * DD * 2;        // 50,724,864
  char* wsb = (char*)d_ws;
  u16* Qb  = (u16*)(wsb);
  u16* Kb  = (u16*)(wsb + QKV_B);
  u16* Vb  = (u16*)(wsb + 2 * QKV_B);
  u16* Vt  = (u16*)(wsb);                              // over dead Qb+Kb head
  u16* O   = (u16*)(wsb + (size_t)BB * DD * TP * 2);   // @62,914,560
  u16* Wot = (u16*)(wsb + 3 * QKV_B);                  // @152,174,592

  u16*   Ab  = (u16*)d_out;                            // live conv_x -> G1
  u16*   S   = (u16*)d_out;                            // live G2a -> softmax (bf16)
  u16*   P   = (u16*)((char*)d_out + QKV_B);           // live softmax -> G2c
  u16*   Wqt = (u16*)((char*)d_out + 97124352);        // live conv_w -> G1
  u16*   Wkt = Wqt + (size_t)DD * DD;
  u16*   Wvt = Wkt + (size_t)DD * DD;

  conv_x<<<2048, 256, 0, stream>>>(x, mem, Ab);
  conv_w<<<1024, 256, 0, stream>>>(Wq, Wk, Wv, Wo, Wqt, Wkt, Wvt, Wot);

  // G1: QKV projection  [33024 x 2304] = Ab @ [Wqt|Wkt|Wvt]^T  (+bias, -> bf16)
  gemm256<0><<<dim3(9, 129), 512, 131072, stream>>>(
      Ab, Wqt, Wkt, Wvt, bq, bk, bv, Qb, Kb, Vb, nullptr, 12);

  // G2a: S = Q @ K^T * scale  (per batch, K-rows remapped, pipelined, bf16 out)
  gemm_s<<<dim3(2, 3, BB), 256, 0, stream>>>(Qb, Kb, S);

  // softmax rows -> P (bf16, zero-padded to 320 cols)
  softmax_k<<<8192, 256, 0, stream>>>(S, P);

  // Vt[b][d][t]  (writes over dead Qb/Kb region)
  transpose_v<<<dim3(12, 5, BB), 256, 0, stream>>>(Vb, Vt);

  // G2c: O = P @ Vt^T per batch (pipelined 256-tile, K=320)
  gemm256<2><<<dim3(3, 128), 512, 131072, stream>>>(
      P, Vt, nullptr, nullptr, nullptr, nullptr, nullptr,
      O, nullptr, nullptr, nullptr, 5);

  // G3: out = O @ Wot^T + bo  (fp32)
  gemm256<1><<<dim3(3, 128), 512, 131072, stream>>>(
      O, Wot, nullptr, nullptr, bo, nullptr, nullptr,
      nullptr, nullptr, nullptr, out, 12);
}